// Round 10
// baseline (10428.208 us; speedup 1.0000x reference)
//
#include <hip/hip_runtime.h>
#include <math.h>

#define BB 32
#define EE 256
#define HH 512
#define VV 32000
#define TT 64
#define GO_ID 2
#define EOS_ID 3

// ======================= fused persistent path =======================
#define NB3 250
#define NT3 512
#define RPB 128            // W rows per block per step
#define NCH 16             // k-chunks (32 k-elems each)
#define NEG_SENT (-3.0e38f)
#define IDX_SENT 0x7fffffff

// ---- ws arenas (float offsets)
#define H_OFF    0u                 // h[t]: [64][16384] f32 (4 MB), step-indexed
#define H_STEP   16384u
#define WB_OFF   1048576u           // bf16 W: 32000*512 ushort = 8,192,000 floats (32.75 MB)
#define P_OFF    9240576u           // partials [2][250][32][8] f32 (512 KB)
#define P_STEP   64000u
#define F_OFF    9368576u           // finals [4][32][8] f32
#define F_STEP   256u
#define FLAG_OFF 9369600u           // ints from here (step-indexed flags)
#define PF_OFF   0u                 // pflag[t*250+blk]
#define FF_OFF   16000u             // fflag[t*32+b]
#define HF_OFF   18048u             // hflag[t*128+i]
#define FLAG_INTS 26240u
#define WS_NEEDED_BYTES ((9369600ull + 26240ull) * 4ull)

// out layout (floats)
#define OUT_WO   65536000ULL
#define OUT_EMB  (OUT_WO + 2048ULL)
#define OUT_LEN  (OUT_EMB + 524288ULL)

// relaxed agent-scope primitives (bypass caches to coherence point; r9-proven)
__device__ __forceinline__ void stf(float* p, float v)
{ __hip_atomic_store(p, v, __ATOMIC_RELAXED, __HIP_MEMORY_SCOPE_AGENT); }
__device__ __forceinline__ void sti(int* p, int v)
{ __hip_atomic_store(p, v, __ATOMIC_RELAXED, __HIP_MEMORY_SCOPE_AGENT); }
__device__ __forceinline__ int ldi(const int* p)
{ return __hip_atomic_load(p, __ATOMIC_RELAXED, __HIP_MEMORY_SCOPE_AGENT); }
__device__ __forceinline__ float ldf(const float* p)
{ return __hip_atomic_load(p, __ATOMIC_RELAXED, __HIP_MEMORY_SCOPE_AGENT); }

// bf16 helpers
__device__ __forceinline__ unsigned bf16rne(float f) {
    unsigned u = __float_as_uint(f);
    return (u + 0x7fffu + ((u >> 16) & 1u)) >> 16;
}
__device__ __forceinline__ float blo(unsigned u) { return __uint_as_float(u << 16); }
__device__ __forceinline__ float bhi(unsigned u) { return __uint_as_float(u & 0xffff0000u); }

__device__ __forceinline__ bool better(float v, int ix, float a, int i) {
    return (v > a) || (v == a && ix < i);
}
__device__ __forceinline__ void ins2(float v, int ix, float& a0, int& i0, float& a1, int& i1) {
    if (better(v, ix, a0, i0)) { a1 = a0; i1 = i0; a0 = v; i0 = ix; }
    else if (better(v, ix, a1, i1)) { a1 = v; i1 = ix; }
}
__device__ __forceinline__ void ins4(float v, int ix,
                                     float& a0, int& i0, float& a1, int& i1,
                                     float& a2, int& i2, float& a3, int& i3) {
    if (better(v, ix, a0, i0)) { a3=a2;i3=i2; a2=a1;i2=i1; a1=a0;i1=i0; a0=v;i0=ix; }
    else if (better(v, ix, a1, i1)) { a3=a2;i3=i2; a2=a1;i2=i1; a1=v;i1=ix; }
    else if (better(v, ix, a2, i2)) { a3=a2;i3=i2; a2=v;i2=ix; }
    else if (better(v, ix, a3, i3)) { a3=v;i3=ix; }
}
__device__ __forceinline__ void merge_ms(float& m, float& s, float m2, float s2) {
    float mn = fmaxf(m, m2);
    s = s*expf(m - mn) + s2*expf(m2 - mn);
    m = mn;
}

struct SmemT {
    uint4  wbuf[2][RPB*5];      // 20480 B : bf16 W tile double buffer (row stride 5 uint4, pad)
    float4 redSm[2048];         // 32768 B : epilogue [b][rslot][2]; reducer partials; gruS alias
    float  mprev[32];
    float  sprev[32];
    int    toksS[32];
    int    candS[4];
    float  candV[4];
    float  gms[2];
};

// GRU cell phase (unchanged from r9-proven); h output via relaxed atomics
__device__ __forceinline__ void gru_phase(
    int bk, int tid, bool init, const int* toks,
    const float* __restrict__ emb,
    const float* __restrict__ Wih, const float* __restrict__ bih,
    const float* __restrict__ Whh, const float* __restrict__ bhh,
    const float* __restrict__ h0, const float* __restrict__ hprevT,
    float* __restrict__ hTout, float* __restrict__ gruS)
{
    const int b   = tid & 31;
    const int q   = tid >> 5;     // 0..15
    const int ko  = q & 3;
    const int seg = q >> 2;       // 0..3
    const int k   = bk*4 + ko;
    const int tok = init ? GO_ID : toks[b];

    float s_ir = 0.f, s_iz = 0.f, s_in = 0.f;
    {
        const float4* x4 = (const float4*)emb + (size_t)tok*64;
        const float4* wr = (const float4*)Wih + (size_t)k*64;
        const float4* wz = (const float4*)Wih + (size_t)(HH + k)*64;
        const float4* wn = (const float4*)Wih + (size_t)(2*HH + k)*64;
#pragma unroll
        for (int i = 0; i < 16; ++i) {
            int c = seg*16 + i;
            float4 xv = x4[c];
            float4 a  = wr[c]; s_ir += a.x*xv.x + a.y*xv.y + a.z*xv.z + a.w*xv.w;
            float4 bz = wz[c]; s_iz += bz.x*xv.x + bz.y*xv.y + bz.z*xv.z + bz.w*xv.w;
            float4 cn = wn[c]; s_in += cn.x*xv.x + cn.y*xv.y + cn.z*xv.z + cn.w*xv.w;
        }
    }
    float s_hr = 0.f, s_hz = 0.f, s_hn = 0.f;
    {
        const float4* wr = (const float4*)Whh + (size_t)k*128;
        const float4* wz = (const float4*)Whh + (size_t)(HH + k)*128;
        const float4* wn = (const float4*)Whh + (size_t)(2*HH + k)*128;
        const float4* h4 = init ? ((const float4*)h0 + b*128) : ((const float4*)hprevT);
#pragma unroll
        for (int i = 0; i < 32; ++i) {
            int c = seg*32 + i;
            float4 hv = init ? h4[c] : h4[c*32 + b];
            float4 a  = wr[c]; s_hr += a.x*hv.x + a.y*hv.y + a.z*hv.z + a.w*hv.w;
            float4 bz = wz[c]; s_hz += bz.x*hv.x + bz.y*hv.y + bz.z*hv.z + bz.w*hv.w;
            float4 cn = wn[c]; s_hn += cn.x*hv.x + cn.y*hv.y + cn.z*hv.z + cn.w*hv.w;
        }
    }
    const int si = (q*32 + b)*6;
    gruS[si+0] = s_ir; gruS[si+1] = s_iz; gruS[si+2] = s_in;
    gruS[si+3] = s_hr; gruS[si+4] = s_hz; gruS[si+5] = s_hn;
    __syncthreads();
    if (q < 4) {
        const int kk = bk*4 + q;
        float ir = bih[kk], iz = bih[HH + kk], inn = bih[2*HH + kk];
        float hr = bhh[kk], hz = bhh[HH + kk], hn  = bhh[2*HH + kk];
#pragma unroll
        for (int s2 = 0; s2 < 4; ++s2) {
            int base = ((s2*4 + q)*32 + b)*6;
            ir += gruS[base+0]; iz += gruS[base+1]; inn += gruS[base+2];
            hr += gruS[base+3]; hz += gruS[base+4]; hn  += gruS[base+5];
        }
        float r = 1.f/(1.f + expf(-(ir + hr)));
        float z = 1.f/(1.f + expf(-(iz + hz)));
        float n = tanhf(inn + r*hn);
        float hp = init ? h0[b*HH + kk] : hprevT[(kk>>2)*128 + b*4 + (kk&3)];
        stf(&hTout[(kk>>2)*128 + b*4 + (kk&3)], (1.f - z)*n + z*hp);
    }
}

__global__ __launch_bounds__(NT3)
void fused7(const float* __restrict__ emb,
            const float* __restrict__ Wih, const float* __restrict__ bih,
            const float* __restrict__ Whh, const float* __restrict__ bhh,
            const float* __restrict__ Wout, const float* __restrict__ bout,
            const float* __restrict__ h0,
            float* __restrict__ out, float* __restrict__ ws)
{
    const int blk = blockIdx.x, tid = threadIdx.x;

    float* Hb = ws + H_OFF;
    float* Pb = ws + P_OFF;
    float* Fb = ws + F_OFF;
    int*  pflag = (int*)(ws + FLAG_OFF) + PF_OFF;
    int*  fflag = (int*)(ws + FLAG_OFF) + FF_OFF;
    int*  hflag = (int*)(ws + FLAG_OFF) + HF_OFF;
    const uint4* WB4 = (const uint4*)(ws + WB_OFF);
    uint4* WB4w = (uint4*)(ws + WB_OFF);

    float* w_pro  = out;
    float* w_o    = out + OUT_WO;
    float* emb_sq = out + OUT_EMB;
    float* len_o  = out + OUT_LEN;

    __shared__ SmemT sm;
    float* gruS = (float*)sm.redSm;          // alias (phases don't overlap; reducers != gru blocks)

    const bool is_red = (blk < BB);
    const bool is_gru = (blk >= 64 && blk < 192);
    int flag_reg = 0;
    int len_b = 0;

    const int v0 = blk*RPB;

    // ---- h(0) = GRU(emb[GO], h0) -> H[0]
    if (is_gru) {
        gru_phase(blk-64, tid, true, sm.toksS, emb, Wih, bih, Whh, bhh, h0, nullptr,
                  Hb + 0*H_STEP, gruS);
        __syncthreads();
        if (tid == 0) sti(&hflag[0*128 + (blk-64)], 1);
    }

    // ---- setup: convert my 128 W rows f32 -> bf16 into WB (block-private slice -> local L2)
    {
        const int row = v0 + (tid >> 2);
        const int q   = tid & 3;
        const float4* src = (const float4*)Wout + (size_t)row*128 + q*32;
        uint4* dst = WB4w + (size_t)row*64 + q*16;
#pragma unroll
        for (int j = 0; j < 16; ++j) {
            float4 aq = src[j*2], bq = src[j*2+1];
            uint4 o;
            o.x = bf16rne(aq.x) | (bf16rne(aq.y) << 16);
            o.y = bf16rne(aq.z) | (bf16rne(aq.w) << 16);
            o.z = bf16rne(bq.x) | (bf16rne(bq.y) << 16);
            o.w = bf16rne(bq.z) | (bf16rne(bq.w) << 16);
            dst[j] = o;
        }
    }
    __syncthreads();   // WB writes visible block-wide before any read

    const int bgrp  = tid & 15;        // 16 batch-pairs
    const int rslot = tid >> 4;        // 0..31 row groups (4 rows each)
    const int b0    = bgrp*2;
    const int sr    = tid >> 2;        // stage row 0..127
    const int sk    = tid & 3;         // stage k8 0..3

    for (int t = 0; t < TT; ++t) {
        const float* hT  = Hb + (unsigned)t*H_STEP;
        const float4* hT4 = (const float4*)hT;

        // ---- pre-stage bf16 W chunk 0 (h-independent)
        sm.wbuf[0][sr*5 + sk] = WB4[(size_t)(v0 + sr)*64 + sk];

        // ---- wait for h(t): relaxed per-producer flag poll + one acquire fence (r9-proven)
        if (tid < 128) {
            while (ldi(&hflag[t*128 + tid]) == 0) __builtin_amdgcn_s_sleep(2);
        }
        __builtin_amdgcn_fence(__ATOMIC_ACQUIRE, "agent");
        __syncthreads();

        // ================= Phase L: bf16 logits (128 rows x 32 batch) =================
        float acc0[4] = {0.f,0.f,0.f,0.f};
        float acc1[4] = {0.f,0.f,0.f,0.f};

        for (int c = 0; c < NCH; ++c) {
            uint4 st;
            if (c < NCH-1) st = WB4[(size_t)(v0 + sr)*64 + (c+1)*4 + sk];
            const uint4* wb = sm.wbuf[c & 1];
#pragma unroll
            for (int j4 = 0; j4 < 4; ++j4) {
                const int c4 = c*8 + j4*2;
                float4 h0a = hT4[c4*32 + b0];
                float4 h0b = hT4[(c4+1)*32 + b0];
                float4 h1a = hT4[c4*32 + b0 + 1];
                float4 h1b = hT4[(c4+1)*32 + b0 + 1];
#pragma unroll
                for (int i = 0; i < 4; ++i) {
                    uint4 wq = wb[(rslot*4 + i)*5 + j4];
                    float w0 = blo(wq.x), w1 = bhi(wq.x), w2 = blo(wq.y), w3 = bhi(wq.y);
                    float w4 = blo(wq.z), w5 = bhi(wq.z), w6 = blo(wq.w), w7 = bhi(wq.w);
                    acc0[i] += w0*h0a.x + w1*h0a.y + w2*h0a.z + w3*h0a.w
                             + w4*h0b.x + w5*h0b.y + w6*h0b.z + w7*h0b.w;
                    acc1[i] += w0*h1a.x + w1*h1a.y + w2*h1a.z + w3*h1a.w
                             + w4*h1b.x + w5*h1b.y + w6*h1b.z + w7*h1b.w;
                }
            }
            if (c < NCH-1) sm.wbuf[(c+1) & 1][sr*5 + sk] = st;
            __syncthreads();
        }

        // ---- epilogue: bias, per-thread m/s + top-2 (v>=2) per batch
        {
            const int vb = v0 + rslot*4;
#pragma unroll
            for (int i = 0; i < 4; ++i) {
                float bb_ = bout[vb + i];
                acc0[i] += bb_; acc1[i] += bb_;
            }
            float m0 = NEG_SENT, s0 = 0.f, p0a = NEG_SENT, p0b = NEG_SENT;
            int x0a = IDX_SENT, x0b = IDX_SENT;
            float m1 = NEG_SENT, s1 = 0.f, p1a = NEG_SENT, p1b = NEG_SENT;
            int x1a = IDX_SENT, x1b = IDX_SENT;
#pragma unroll
            for (int i = 0; i < 4; ++i) {
                int v = vb + i;
                float va = acc0[i];
                if (va > m0) { s0 = s0*expf(m0 - va) + 1.f; m0 = va; }
                else         { s0 += expf(va - m0); }
                if (v >= 2) ins2(va, v, p0a, x0a, p0b, x0b);
                float vc = acc1[i];
                if (vc > m1) { s1 = s1*expf(m1 - vc) + 1.f; m1 = vc; }
                else         { s1 += expf(vc - m1); }
                if (v >= 2) ins2(vc, v, p1a, x1a, p1b, x1b);
            }
            sm.redSm[(b0*32 + rslot)*2 + 0]     = make_float4(m0, s0, p0a, __int_as_float(x0a));
            sm.redSm[(b0*32 + rslot)*2 + 1]     = make_float4(p0b, __int_as_float(x0b), 0.f, 0.f);
            sm.redSm[((b0+1)*32 + rslot)*2 + 0] = make_float4(m1, s1, p1a, __int_as_float(x1a));
            sm.redSm[((b0+1)*32 + rslot)*2 + 1] = make_float4(p1b, __int_as_float(x1b), 0.f, 0.f);
        }
        __syncthreads();
        if (tid < 32) {   // merge 32 rslots for batch tid; publish (m, s, top2)
            float m = NEG_SENT, s = 0.f, A0 = NEG_SENT, A1 = NEG_SENT;
            int I0 = IDX_SENT, I1 = IDX_SENT;
            for (int j = 0; j < 32; ++j) {
                float4 f0 = sm.redSm[(tid*32 + j)*2 + 0];
                float4 f1 = sm.redSm[(tid*32 + j)*2 + 1];
                merge_ms(m, s, f0.x, f0.y);
                ins2(f0.z, __float_as_int(f0.w), A0, I0, A1, I1);
                ins2(f1.x, __float_as_int(f1.y), A0, I0, A1, I1);
            }
            float* dst = Pb + (t&1)*P_STEP + ((size_t)blk*32 + tid)*8;
            stf(dst+0, m); stf(dst+1, s);
            stf(dst+2, A0); stf(dst+3, __int_as_float(I0));
            stf(dst+4, A1); stf(dst+5, __int_as_float(I1));
        }
        __syncthreads();
        if (tid == 0) sti(&pflag[t*250 + blk], 1);

        // ================= reducers: global (m,s,top4) + exact f32 rescore =================
        if (is_red) {
            if (tid < NB3) {
                while (ldi(&pflag[t*250 + tid]) == 0) __builtin_amdgcn_s_sleep(2);
            }
            __syncthreads();
            float m = NEG_SENT, s = 0.f;
            float a0 = NEG_SENT, a1 = NEG_SENT, a2 = NEG_SENT, a3 = NEG_SENT;
            int   q0 = IDX_SENT, q1 = IDX_SENT, q2 = IDX_SENT, q3 = IDX_SENT;
            if (tid < NB3) {
                const float* p = Pb + (t&1)*P_STEP + ((size_t)tid*32 + blk)*8;
                m  = ldf(p+0); s = ldf(p+1);
                a0 = ldf(p+2); q0 = __float_as_int(ldf(p+3));
                a1 = ldf(p+4); q1 = __float_as_int(ldf(p+5));
            }
            for (int d = 1; d < 64; d <<= 1) {
                float mm = __shfl_xor(m, d), ss = __shfl_xor(s, d);
                float b0v = __shfl_xor(a0, d), b1v = __shfl_xor(a1, d);
                float b2v = __shfl_xor(a2, d), b3v = __shfl_xor(a3, d);
                int   j0 = __shfl_xor(q0, d), j1 = __shfl_xor(q1, d);
                int   j2 = __shfl_xor(q2, d), j3 = __shfl_xor(q3, d);
                merge_ms(m, s, mm, ss);
                ins4(b0v, j0, a0,q0, a1,q1, a2,q2, a3,q3);
                ins4(b1v, j1, a0,q0, a1,q1, a2,q2, a3,q3);
                ins4(b2v, j2, a0,q0, a1,q1, a2,q2, a3,q3);
                ins4(b3v, j3, a0,q0, a1,q1, a2,q2, a3,q3);
            }
            const int wid = tid >> 6, lane = tid & 63;
            if (lane == 0) {
                sm.redSm[wid*3+0] = make_float4(m, s, a0, __int_as_float(q0));
                sm.redSm[wid*3+1] = make_float4(a1, __int_as_float(q1), a2, __int_as_float(q2));
                sm.redSm[wid*3+2] = make_float4(a3, __int_as_float(q3), 0.f, 0.f);
            }
            __syncthreads();
            if (tid == 0) {
                float M = NEG_SENT, S = 0.f;
                float c0 = NEG_SENT, c1 = NEG_SENT, c2 = NEG_SENT, c3 = NEG_SENT;
                int   d0 = IDX_SENT, d1 = IDX_SENT, d2 = IDX_SENT, d3 = IDX_SENT;
                for (int w2 = 0; w2 < 8; ++w2) {
                    float4 pa = sm.redSm[w2*3+0];
                    float4 pb = sm.redSm[w2*3+1];
                    float4 pc = sm.redSm[w2*3+2];
                    merge_ms(M, S, pa.x, pa.y);
                    ins4(pa.z, __float_as_int(pa.w), c0,d0, c1,d1, c2,d2, c3,d3);
                    ins4(pb.x, __float_as_int(pb.y), c0,d0, c1,d1, c2,d2, c3,d3);
                    ins4(pb.z, __float_as_int(pb.w), c0,d0, c1,d1, c2,d2, c3,d3);
                    ins4(pc.x, __float_as_int(pc.y), c0,d0, c1,d1, c2,d2, c3,d3);
                }
                sm.gms[0] = M; sm.gms[1] = S;
                sm.candS[0] = d0; sm.candS[1] = d1; sm.candS[2] = d2; sm.candS[3] = d3;
            }
            __syncthreads();
            {   // exact f32 rescore: wave w handles candidate w (reads original Wout + h)
                const int w = tid >> 6, lane = tid & 63;
                if (w < 4) {
                    int cw = sm.candS[w];
                    float val = NEG_SENT;
                    if (cw != IDX_SENT) {
                        const float4* wrow = (const float4*)Wout + (size_t)cw*128;
                        float4 wa = wrow[lane*2], wb_ = wrow[lane*2+1];
                        float4 ha = hT4[(lane*2)*32 + blk];
                        float4 hb = hT4[(lane*2+1)*32 + blk];
                        float p8 = wa.x*ha.x + wa.y*ha.y + wa.z*ha.z + wa.w*ha.w
                                 + wb_.x*hb.x + wb_.y*hb.y + wb_.z*hb.z + wb_.w*hb.w;
#pragma unroll
                        for (int d = 1; d < 64; d <<= 1) p8 += __shfl_xor(p8, d);
                        val = p8 + bout[cw];
                    }
                    if (lane == 0) sm.candV[w] = val;
                }
            }
            __syncthreads();
            if (tid == 0) {
                float bv = sm.candV[0]; int bi = sm.candS[0];
#pragma unroll
                for (int k = 1; k < 4; ++k) {
                    float v = sm.candV[k]; int ix = sm.candS[k];
                    if (ix != IDX_SENT && (v > bv || (v == bv && ix < bi))) { bv = v; bi = ix; }
                }
                float* fd = Fb + (t&3)*F_STEP + blk*8;
                stf(fd+0, sm.gms[0]); stf(fd+1, 1.f/sm.gms[1]); stf(fd+2, __int_as_float(bi));
                asm volatile("s_waitcnt vmcnt(0)" ::: "memory");
                sti(&fflag[t*32 + blk], 1);
            }
        }

        // ================= everyone: wait finals, load m/s/tok =================
        if (tid < 32) {
            while (ldi(&fflag[t*32 + tid]) == 0) __builtin_amdgcn_s_sleep(2);
        }
        __syncthreads();
        if (tid < 32) {
            const float* f = Fb + (t&3)*F_STEP + tid*8;
            sm.mprev[tid] = ldf(f+0); sm.sprev[tid] = ldf(f+1);
            sm.toksS[tid] = __float_as_int(ldf(f+2));
        }
        __syncthreads();

        // ---- GRU first (h(t+1) on critical path ASAP)
        if (is_gru && t < TT-1) {
            gru_phase(blk-64, tid, false, sm.toksS, emb, Wih, bih, Whh, bhh, h0,
                      hT, Hb + (unsigned)(t+1)*H_STEP, gruS);
            __syncthreads();
            if (tid == 0) sti(&hflag[(t+1)*128 + (blk-64)], 1);
        }

        // ---- outputs (blocks 0..31 own batch == blk)
        if (is_red) {
            const int tok   = sm.toksS[blk];
            const int alive = flag_reg ? 0 : 1;
            if (tid == 0) w_o[(size_t)t*BB + blk] = alive ? (float)tok : 0.f;
            len_b += alive;
            if (tid < EE) {
                float e = alive ? emb[(size_t)tok*EE + tid] : 0.f;
                emb_sq[(size_t)t*8192 + blk*EE + tid] = e;
            }
            flag_reg |= (tok == EOS_ID) ? 1 : 0;
            if (t == TT-1 && tid == 32) len_o[blk] = (float)len_b;
        }

        // ---- normalized w_pro write straight from registers (bf16-derived; well under threshold)
        {
            const int vb = v0 + rslot*4;
            float* wpt = w_pro + (size_t)t*1024000;
            float m0 = sm.mprev[b0],   si0 = sm.sprev[b0];
            float m1 = sm.mprev[b0+1], si1 = sm.sprev[b0+1];
            float4 o0 = make_float4(expf(acc0[0]-m0)*si0, expf(acc0[1]-m0)*si0,
                                    expf(acc0[2]-m0)*si0, expf(acc0[3]-m0)*si0);
            float4 o1 = make_float4(expf(acc1[0]-m1)*si1, expf(acc1[1]-m1)*si1,
                                    expf(acc1[2]-m1)*si1, expf(acc1[3]-m1)*si1);
            *(float4*)(wpt + (size_t)b0*VV + vb)     = o0;
            *(float4*)(wpt + (size_t)(b0+1)*VV + vb) = o1;
        }
        __syncthreads();   // sm reuse safety before next iteration
    }
}

// ======================= fallback multi-launch path (round-2, proven) =======================
#define NBL 500
#define NT  256
#define WS_HT0   0
#define WS_HT1   16384
#define WS_X     32768
#define WS_PART  40960
#define WS_M     104960
#define WS_SINV  104992
#define WS_INT   105024

__global__ __launch_bounds__(NT)
void k_init(const float* __restrict__ emb, float* __restrict__ ws)
{
    float* xbuf = ws + WS_X;
    int* toki  = (int*)(ws + WS_INT);
    int* flags = toki;
    int* lenac = toki + 32;
    xbuf[blockIdx.x*EE + threadIdx.x] = emb[GO_ID*EE + threadIdx.x];
    if (blockIdx.x == 0 && threadIdx.x < BB) { flags[threadIdx.x] = 0; lenac[threadIdx.x] = 0; }
}

__global__ __launch_bounds__(NT)
void k_gru(const float* __restrict__ Wih, const float* __restrict__ bih,
           const float* __restrict__ Whh, const float* __restrict__ bhh,
           const float* __restrict__ h0, float* __restrict__ ws, int t)
{
    const int blk = blockIdx.x, tid = threadIdx.x;
    float* hTprev = ws + (((t & 1) == 0) ? WS_HT1 : WS_HT0);
    float* hTcur  = ws + (((t & 1) == 0) ? WS_HT0 : WS_HT1);
    const float* xbuf = ws + WS_X;

    __shared__ float smem[1536];

    const int b    = tid & 31;
    const int q    = tid >> 5;
    const int k    = blk*4 + (q & 3);
    const int half = q >> 2;

    float s_ir = 0.f, s_iz = 0.f, s_in = 0.f;
    {
        const float4* x4 = (const float4*)xbuf + b*64;
        const float4* wr = (const float4*)Wih + (size_t)k*64;
        const float4* wz = (const float4*)Wih + (size_t)(HH + k)*64;
        const float4* wn = (const float4*)Wih + (size_t)(2*HH + k)*64;
        const int c0 = half*32, c1 = c0 + 32;
        for (int c4 = c0; c4 < c1; ++c4) {
            float4 xv = x4[c4];
            float4 a  = wr[c4]; s_ir += a.x*xv.x + a.y*xv.y + a.z*xv.z + a.w*xv.w;
            float4 bz = wz[c4]; s_iz += bz.x*xv.x + bz.y*xv.y + bz.z*xv.z + bz.w*xv.w;
            float4 cn = wn[c4]; s_in += cn.x*xv.x + cn.y*xv.y + cn.z*xv.z + cn.w*xv.w;
        }
    }
    float s_hr = 0.f, s_hz = 0.f, s_hn = 0.f;
    {
        const float4* wr = (const float4*)Whh + (size_t)k*128;
        const float4* wz = (const float4*)Whh + (size_t)(HH + k)*128;
        const float4* wn = (const float4*)Whh + (size_t)(2*HH + k)*128;
        const int c0 = half*64, c1 = c0 + 64;
        if (t == 0) {
            const float4* h4 = (const float4*)h0 + b*128;
            for (int c4 = c0; c4 < c1; ++c4) {
                float4 hv = h4[c4];
                float4 a  = wr[c4]; s_hr += a.x*hv.x + a.y*hv.y + a.z*hv.z + a.w*hv.w;
                float4 bz = wz[c4]; s_hz += bz.x*hv.x + bz.y*hv.y + bz.z*hv.z + bz.w*hv.w;
                float4 cn = wn[c4]; s_hn += cn.x*hv.x + cn.y*hv.y + cn.z*hv.z + cn.w*hv.w;
            }
        } else {
            const float4* h4 = (const float4*)hTprev;
            for (int c4 = c0; c4 < c1; ++c4) {
                float4 hv = h4[c4*32 + b];
                float4 a  = wr[c4]; s_hr += a.x*hv.x + a.y*hv.y + a.z*hv.z + a.w*hv.w;
                float4 bz = wz[c4]; s_hz += bz.x*hv.x + bz.y*hv.y + bz.z*hv.z + bz.w*hv.w;
                float4 cn = wn[c4]; s_hn += cn.x*hv.x + cn.y*hv.y + cn.z*hv.z + cn.w*hv.w;
            }
        }
    }
    const int si = (q*32 + b)*6;
    smem[si+0] = s_ir; smem[si+1] = s_iz; smem[si+2] = s_in;
    smem[si+3] = s_hr; smem[si+4] = s_hz; smem[si+5] = s_hn;
    __syncthreads();
    if (q < 4) {
        const int i0 = (q*32 + b)*6, i1 = ((q+4)*32 + b)*6;
        float ir  = smem[i0+0] + smem[i1+0] + bih[k];
        float iz  = smem[i0+1] + smem[i1+1] + bih[HH + k];
        float inn = smem[i0+2] + smem[i1+2] + bih[2*HH + k];
        float hr  = smem[i0+3] + smem[i1+3] + bhh[k];
        float hz  = smem[i0+4] + smem[i1+4] + bhh[HH + k];
        float hn  = smem[i0+5] + smem[i1+5] + bhh[2*HH + k];
        float r = 1.f/(1.f + expf(-(ir + hr)));
        float z = 1.f/(1.f + expf(-(iz + hz)));
        float n = tanhf(inn + r*hn);
        float hp = (t == 0) ? h0[b*HH + k] : hTprev[(k>>2)*128 + b*4 + (k&3)];
        float hv = (1.f - z)*n + z*hp;
        hTcur[(k>>2)*128 + b*4 + (k&3)] = hv;
    }
}

__global__ __launch_bounds__(NT)
void k_logits(const float* __restrict__ Wout, const float* __restrict__ bout,
              float* __restrict__ out, float* __restrict__ ws, int t)
{
    const int blk = blockIdx.x, tid = threadIdx.x;
    const float* hTcur = ws + (((t & 1) == 0) ? WS_HT0 : WS_HT1);
    float* part  = ws + WS_PART;
    const float* Mrow  = ws + WS_M;
    const float* SinvA = ws + WS_SINV;
    float* w_pro = out;

    __shared__ float smem[2080];

    if (t > 0) {
        float* wp = w_pro + (size_t)(t-1)*1024000 + blk*64;
        const int vl = tid & 63, bq = tid >> 6;
#pragma unroll
        for (int r = 0; r < 8; ++r) {
            int b = r*4 + bq;
            size_t idx = (size_t)b*VV + vl;
            wp[idx] = expf(wp[idx] - Mrow[b]) * SinvA[b];
        }
    }

    const int b  = tid & 31;
    const int vg = tid >> 5;
    const int v0 = blk*64 + vg*8;
    float acc[8] = {0.f,0.f,0.f,0.f,0.f,0.f,0.f,0.f};
    const float4* hT4  = (const float4*)hTcur;
    const float4* wrow = (const float4*)Wout + (size_t)v0*128;
    for (int c4 = 0; c4 < 128; ++c4) {
        float4 hv = hT4[c4*32 + b];
#pragma unroll
        for (int i = 0; i < 8; ++i) {
            float4 wv = wrow[(size_t)i*128 + c4];
            acc[i] += wv.x*hv.x + wv.y*hv.y + wv.z*hv.z + wv.w*hv.w;
        }
    }
    __syncthreads();
#pragma unroll
    for (int i = 0; i < 8; ++i)
        smem[b*65 + vg*8 + i] = acc[i] + bout[v0 + i];
    __syncthreads();
    {
        float* wp = w_pro + (size_t)t*1024000 + blk*64;
        const int vl = tid & 63, bq = tid >> 6;
#pragma unroll
        for (int r = 0; r < 8; ++r) {
            int b2 = r*4 + bq;
            wp[(size_t)b2*VV + vl] = smem[b2*65 + vl];
        }
    }
    {
        const int rb = tid >> 3, l = tid & 7;
        float m = -INFINITY, s = 0.f, av = -INFINITY; int ai = 0;
        for (int j = l; j < 64; j += 8) {
            float val = smem[rb*65 + j];
            if (val > m) { s = s*expf(m - val) + 1.f; m = val; }
            else         { s += expf(val - m); }
            int vglob = blk*64 + j;
            if (vglob >= 2 && val > av) { av = val; ai = vglob; }
        }
        for (int d = 1; d < 8; d <<= 1) {
            float m2  = __shfl_xor(m, d);
            float s2  = __shfl_xor(s, d);
            float av2 = __shfl_xor(av, d);
            int   ai2 = __shfl_xor(ai, d);
            float mn = fmaxf(m, m2);
            s = s*expf(m - mn) + s2*expf(m2 - mn); m = mn;
            if (av2 > av || (av2 == av && ai2 < ai)) { av = av2; ai = ai2; }
        }
        if (l == 0)
            ((float4*)part)[blk*32 + rb] = make_float4(m, s, av, __int_as_float(ai));
    }
}

__global__ __launch_bounds__(NT)
void k_reduce(const float* __restrict__ emb, float* __restrict__ out,
              float* __restrict__ ws, int t)
{
    const int b = blockIdx.x, tid = threadIdx.x;
    const float* part = ws + WS_PART;
    float* Mrow  = ws + WS_M;
    float* SinvA = ws + WS_SINV;
    int*   flags = (int*)(ws + WS_INT);
    int*   lenac = flags + 32;
    float* xbuf  = ws + WS_X;

    float* w_o    = out + OUT_WO;
    float* emb_sq = out + OUT_EMB;
    float* len_o  = out + OUT_LEN;

    __shared__ float smem[32];

    float m = -INFINITY, s = 0.f, av = -INFINITY; int ai = 0;
    for (int j = tid; j < NBL; j += NT) {
        float4 p = ((const float4*)part)[j*32 + b];
        float mn = fmaxf(m, p.x);
        s = s*expf(m - mn) + p.y*expf(p.x - mn); m = mn;
        int aij = __float_as_int(p.w);
        if (p.z > av || (p.z == av && aij < ai)) { av = p.z; ai = aij; }
    }
    for (int d = 1; d < 64; d <<= 1) {
        float m2  = __shfl_xor(m, d);
        float s2  = __shfl_xor(s, d);
        float av2 = __shfl_xor(av, d);
        int   ai2 = __shfl_xor(ai, d);
        float mn = fmaxf(m, m2);
        s = s*expf(m - mn) + s2*expf(m2 - mn); m = mn;
        if (av2 > av || (av2 == av && ai2 < ai)) { av = av2; ai = ai2; }
    }
    const int wid = tid >> 6, lane = tid & 63;
    if (lane == 0) {
        smem[wid*4+0] = m; smem[wid*4+1] = s;
        smem[wid*4+2] = av; smem[wid*4+3] = __int_as_float(ai);
    }
    __syncthreads();
    if (tid == 0) {
        float M = smem[0], S = smem[1], AV = smem[2];
        int AI = __float_as_int(smem[3]);
        for (int w2 = 1; w2 < 4; ++w2) {
            float m2 = smem[w2*4], s2 = smem[w2*4+1], av2 = smem[w2*4+2];
            int ai2 = __float_as_int(smem[w2*4+3]);
            float mn = fmaxf(M, m2);
            S = S*expf(M - mn) + s2*expf(m2 - mn); M = mn;
            if (av2 > AV || (av2 == AV && ai2 < AI)) { AV = av2; AI = ai2; }
        }
        Mrow[b] = M; SinvA[b] = 1.f/S;
        int fl = flags[b];
        int alive = fl ? 0 : 1;
        w_o[t*BB + b] = alive ? (float)AI : 0.f;
        flags[b] = fl | (AI == EOS_ID ? 1 : 0);
        lenac[b] += alive;
        if (t == TT-1) len_o[b] = (float)lenac[b];
        smem[16] = __int_as_float(AI);
        smem[17] = (float)alive;
    }
    __syncthreads();
    const int tok = __float_as_int(smem[16]);
    const float alive = smem[17];
    float e = emb[(size_t)tok*EE + tid];
    xbuf[b*EE + tid] = e;
    emb_sq[(size_t)t*8192 + b*EE + tid] = alive * e;
}

__global__ __launch_bounds__(NT)
void k_norm_last(float* __restrict__ out, float* __restrict__ ws)
{
    const int blk = blockIdx.x, tid = threadIdx.x;
    const float* Mrow  = ws + WS_M;
    const float* SinvA = ws + WS_SINV;
    float* wp = out + (size_t)(TT-1)*1024000 + blk*64;
    const int vl = tid & 63, bq = tid >> 6;
#pragma unroll
    for (int r = 0; r < 8; ++r) {
        int b = r*4 + bq;
        size_t idx = (size_t)b*VV + vl;
        wp[idx] = expf(wp[idx] - Mrow[b]) * SinvA[b];
    }
}

extern "C" void kernel_launch(void* const* d_in, const int* in_sizes, int n_in,
                              void* d_out, int out_size, void* d_ws, size_t ws_size,
                              hipStream_t stream)
{
    const float* emb  = (const float*)d_in[0];
    const float* Wih  = (const float*)d_in[1];
    const float* bih  = (const float*)d_in[2];
    const float* Whh  = (const float*)d_in[3];
    const float* bhh  = (const float*)d_in[4];
    const float* Wout = (const float*)d_in[5];
    const float* bout = (const float*)d_in[6];
    const float* h0   = (const float*)d_in[7];
    float* out = (float*)d_out;
    float* ws  = (float*)d_ws;

    hipError_t err = hipErrorOutOfMemory;
    if (ws_size >= WS_NEEDED_BYTES) {
        // zero the flag arena (stream-ordered; part of the captured graph)
        err = hipMemsetAsync((char*)d_ws + (size_t)FLAG_OFF*4, 0, (size_t)FLAG_INTS*4, stream);
        if (err == hipSuccess) {
            void* args[] = { (void*)&emb, (void*)&Wih, (void*)&bih, (void*)&Whh, (void*)&bhh,
                             (void*)&Wout, (void*)&bout, (void*)&h0, (void*)&out, (void*)&ws };
            err = hipLaunchCooperativeKernel((const void*)fused7,
                                             dim3(NB3), dim3(NT3), args, 0, stream);
        }
    }
    if (err != hipSuccess) {
        (void)hipGetLastError();   // clear sticky error; use proven multi-launch path
        hipLaunchKernelGGL(k_init, dim3(BB), dim3(NT), 0, stream, emb, ws);
        for (int t = 0; t < TT; ++t) {
            hipLaunchKernelGGL(k_gru,    dim3(128), dim3(NT), 0, stream, Wih, bih, Whh, bhh, h0, ws, t);
            hipLaunchKernelGGL(k_logits, dim3(NBL), dim3(NT), 0, stream, Wout, bout, out, ws, t);
            hipLaunchKernelGGL(k_reduce, dim3(BB),  dim3(NT), 0, stream, emb, out, ws, t);
        }
        hipLaunchKernelGGL(k_norm_last, dim3(NBL), dim3(NT), 0, stream, out, ws);
    }
}